// Round 3
// baseline (1812.608 us; speedup 1.0000x reference)
//
#include <hip/hip_runtime.h>
#include <stdint.h>

#define NSAMP 5000
#define BLOCK 256

struct K2 { uint32_t a, b; };

// Threefry-2x32, 20 rounds — matches jax/_src/prng.py lowering exactly.
__device__ __forceinline__ K2 tf(K2 k, uint32_t x0, uint32_t x1) {
  const uint32_t k0 = k.a, k1 = k.b;
  const uint32_t k2 = k0 ^ k1 ^ 0x1BD11BDAu;
  x0 += k0; x1 += k1;
#define R_(r) { x0 += x1; x1 = (x1 << (r)) | (x1 >> (32 - (r))); x1 ^= x0; }
  R_(13) R_(15) R_(26) R_(6)
  x0 += k1; x1 += k2 + 1u;
  R_(17) R_(29) R_(16) R_(24)
  x0 += k2; x1 += k0 + 2u;
  R_(13) R_(15) R_(26) R_(6)
  x0 += k0; x1 += k1 + 3u;
  R_(17) R_(29) R_(16) R_(24)
  x0 += k1; x1 += k2 + 4u;
  R_(13) R_(15) R_(26) R_(6)
  x0 += k2; x1 += k0 + 5u;
#undef R_
  return K2{x0, x1};
}

// Partitionable-mode scalar random_bits(key, 32, ()):
//   counts = (0,0); bits1, bits2 = threefry(key, counts); return bits1 ^ bits2
__device__ __forceinline__ uint32_t draw32(K2 key) {
  K2 r = tf(key, 0u, 0u);
  return r.a ^ r.b;
}

// JAX uniform [0,1): bitcast(0x3F800000 | (bits>>9)) - 1
__device__ __forceinline__ float bits_to_u01(uint32_t bits) {
  return __uint_as_float(0x3F800000u | (bits >> 9)) - 1.0f;
}

// XLA ErfInv32 (Giles polynomial, w = -log1p(-x^2), branch at 5).
__device__ __forceinline__ float erfinv32(float x) {
  float w = -log1pf(-__fmul_rn(x, x));
  float p;
  if (w < 5.0f) {
    w = __fadd_rn(w, -2.5f);
    p = 2.81022636e-08f;
    p = __fadd_rn(3.43273939e-07f, __fmul_rn(p, w));
    p = __fadd_rn(-3.5233877e-06f, __fmul_rn(p, w));
    p = __fadd_rn(-4.39150654e-06f, __fmul_rn(p, w));
    p = __fadd_rn(0.00021858087f,  __fmul_rn(p, w));
    p = __fadd_rn(-0.00125372503f, __fmul_rn(p, w));
    p = __fadd_rn(-0.00417768164f, __fmul_rn(p, w));
    p = __fadd_rn(0.246640727f,    __fmul_rn(p, w));
    p = __fadd_rn(1.50140941f,     __fmul_rn(p, w));
  } else {
    w = __fadd_rn(__fsqrt_rn(w), -3.0f);
    p = -0.000200214257f;
    p = __fadd_rn(0.000100950558f, __fmul_rn(p, w));
    p = __fadd_rn(0.00134934322f,  __fmul_rn(p, w));
    p = __fadd_rn(-0.00367342844f, __fmul_rn(p, w));
    p = __fadd_rn(0.00573950773f,  __fmul_rn(p, w));
    p = __fadd_rn(-0.0076224613f,  __fmul_rn(p, w));
    p = __fadd_rn(0.00943887047f,  __fmul_rn(p, w));
    p = __fadd_rn(1.00167406f,     __fmul_rn(p, w));
    p = __fadd_rn(2.83297682f,     __fmul_rn(p, w));
  }
  return __fmul_rn(p, x);
}

// jax.random.normal scalar: u = u01*2 + nextafter(-1,0); sqrt(2)*erfinv(u)
__device__ __forceinline__ float normal_from_bits(uint32_t bits) {
  const float LO = __uint_as_float(0xBF7FFFFFu);   // nextafter(-1,0)
  float f = bits_to_u01(bits);
  float u = __fadd_rn(__fmul_rn(f, 2.0f), LO);
  u = fmaxf(LO, u);
  return __fmul_rn(__uint_as_float(0x3FB504F3u) /* f32(sqrt(2)) */, erfinv32(u));
}

// JAX _gamma_one, log_space=True, alpha >= 1 (no boost; u_boost subkey value unused).
// Fold-like splits (threefry_partitionable=True): split(key,n)[j] = tf(key,(0,j)).
__device__ float loggamma_one(K2 key_i, float d, float c) {
  // key, subkey = split(key_i); u_boost = uniform(subkey) (unused); carry split[0]
  K2 k = tf(key_i, 0u, 0u);
  float X = 0.0f, V = 1.0f, U = 2.0f;
  while (true) {
    // cond: continue while (U >= 1-0.0331 X^2) && (log U >= X/2 + d(1-V+log V))
    float sq = __fsub_rn(1.0f, __fmul_rn(0.0331f, __fmul_rn(X, X)));
    bool go = false;
    if (U >= sq) {
      float rhs = __fadd_rn(__fmul_rn(X, 0.5f),
                            __fmul_rn(d, __fadd_rn(__fsub_rn(1.0f, V), logf(V))));
      go = (logf(U) >= rhs);
    }
    if (!go) break;
    // body: key, x_key, U_key = split(k, 3)
    K2 xk   = tf(k, 0u, 1u);
    K2 Uk   = tf(k, 0u, 2u);
    K2 knew = tf(k, 0u, 0u);
    k = knew;
    float x, v;
    while (true) {
      // x_key, subkey = split(x_key); x = normal(subkey)
      K2 sk = tf(xk, 0u, 1u);
      x = normal_from_bits(draw32(sk));
      v = __fadd_rn(1.0f, __fmul_rn(x, c));
      if (v > 0.0f) break;
      xk = tf(xk, 0u, 0u);
    }
    X = __fmul_rn(x, x);
    V = __fmul_rn(__fmul_rn(v, v), v);
    U = bits_to_u01(draw32(Uk));
  }
  return __fadd_rn(logf(V), logf(d));
}

__global__ __launch_bounds__(BLOCK) void beta_mc_kernel(
    const float* __restrict__ alpha, const float* __restrict__ beta_,
    const int* __restrict__ cip, const int* __restrict__ valp,
    const int* __restrict__ offp, float* __restrict__ out, int E, int C)
{
  const int e = blockIdx.x;
  const int ci = *cip;
  float thr = __fdiv_rn((float)(*valp + *offp), 1000.0f);
  thr = fminf(fmaxf(thr, 0.0f), 1.0f);

  const float av = alpha[e * C + ci];
  const float bv = beta_[e * C + ci];

  // root key data = (0, 42); key_a, key_b = split(root)  [fold-like]
  const K2 root{0u, 42u};
  const K2 ka = tf(root, 0u, 0u);
  const K2 kb = tf(root, 0u, 1u);

  // Marsaglia-Tsang: d = alpha - 1/3, c = (1/3)/sqrt(d)
  const float ONE3 = 0.33333334f;  // f32(1/3)
  const float da = __fsub_rn(av, ONE3);
  const float ca = __fdiv_rn(ONE3, __fsqrt_rn(da));
  const float db = __fsub_rn(bv, ONE3);
  const float cb = __fdiv_rn(ONE3, __fsqrt_rn(db));

  float acc = 0.0f;
  for (int s = threadIdx.x; s < NSAMP; s += BLOCK) {
    const uint32_t i = (uint32_t)s * (uint32_t)E + (uint32_t)e;  // flat idx in (5000,64,128)
    // per-element keys: split(key_g, N)[i] = tf(key_g, (0, i))  [fold-like]
    const float lga = loggamma_one(tf(ka, 0u, i), da, ca);
    const float lgb = loggamma_one(tf(kb, 0u, i), db, cb);
    // beta combine (log-space, overflow-safe) — matches jax _beta
    const float m  = fmaxf(lga, lgb);
    const float ga = expf(__fsub_rn(lga, m));
    const float gb = expf(__fsub_rn(lgb, m));
    const float x  = __fdiv_rn(ga, __fadd_rn(ga, gb));
    const float z  = __fmul_rn(__fsub_rn(thr, x), 100.0f);
    acc += __fdiv_rn(1.0f, __fadd_rn(1.0f, expf(-z)));
  }

  // block reduction (wave64 shfl + LDS)
  for (int o = 32; o > 0; o >>= 1) acc += __shfl_down(acc, o, 64);
  __shared__ float ws_[BLOCK / 64];
  const int lane = threadIdx.x & 63, wid = threadIdx.x >> 6;
  if (lane == 0) ws_[wid] = acc;
  __syncthreads();
  if (threadIdx.x == 0) {
    float t = 0.0f;
    #pragma unroll
    for (int w = 0; w < BLOCK / 64; ++w) t += ws_[w];
    float p = __fdiv_rn(t, 5000.0f);
    out[e] = fminf(fmaxf(p, 1e-8f), 1.0f - 1e-8f);
  }
}

extern "C" void kernel_launch(void* const* d_in, const int* in_sizes, int n_in,
                              void* d_out, int out_size, void* d_ws, size_t ws_size,
                              hipStream_t stream) {
  const float* alpha = (const float*)d_in[0];
  const float* beta_ = (const float*)d_in[1];
  const int* ci  = (const int*)d_in[2];
  const int* val = (const int*)d_in[3];
  const int* off = (const int*)d_in[4];
  float* out = (float*)d_out;
  const int E = out_size;                 // 64*128 = 8192
  const int C = in_sizes[0] / out_size;   // 4
  beta_mc_kernel<<<dim3(E), dim3(BLOCK), 0, stream>>>(alpha, beta_, ci, val, off, out, E, C);
}

// Round 5
// 1199.619 us; speedup vs baseline: 1.5110x; 1.5110x over previous
//
#include <hip/hip_runtime.h>
#include <stdint.h>

#define NSAMP 5000
#define BLOCK 256

struct K2 { uint32_t a, b; };

// Threefry-2x32, 20 rounds — matches jax/_src/prng.py lowering exactly.
__device__ __forceinline__ K2 tf(K2 k, uint32_t x0, uint32_t x1) {
  const uint32_t k0 = k.a, k1 = k.b;
  const uint32_t k2 = k0 ^ k1 ^ 0x1BD11BDAu;
  x0 += k0; x1 += k1;
#define R_(r) { x0 += x1; x1 = (x1 << (r)) | (x1 >> (32 - (r))); x1 ^= x0; }
  R_(13) R_(15) R_(26) R_(6)
  x0 += k1; x1 += k2 + 1u;
  R_(17) R_(29) R_(16) R_(24)
  x0 += k2; x1 += k0 + 2u;
  R_(13) R_(15) R_(26) R_(6)
  x0 += k0; x1 += k1 + 3u;
  R_(17) R_(29) R_(16) R_(24)
  x0 += k1; x1 += k2 + 4u;
  R_(13) R_(15) R_(26) R_(6)
  x0 += k2; x1 += k0 + 5u;
#undef R_
  return K2{x0, x1};
}

// Partitionable-mode scalar random_bits: xor of both threefry output words.
__device__ __forceinline__ uint32_t draw32(K2 key) {
  K2 r = tf(key, 0u, 0u);
  return r.a ^ r.b;
}

// JAX uniform [0,1): bitcast(0x3F800000 | (bits>>9)) - 1
__device__ __forceinline__ float bits_to_u01(uint32_t bits) {
  return __uint_as_float(0x3F800000u | (bits >> 9)) - 1.0f;
}

// Fast transcendentals via gfx950 HW ops (v_log_f32 / v_exp_f32 / v_rcp_f32).
// ~1 ulp — decision-flip probability ~1e-6/test, harmless vs 2e-2 threshold.
__device__ __forceinline__ float flog(float x) { return __builtin_amdgcn_logf(x) * 0.69314718f; }
__device__ __forceinline__ float fexp(float x) { return __builtin_amdgcn_exp2f(x * 1.44269504f); }
__device__ __forceinline__ float frcp(float x) { return __builtin_amdgcn_rcpf(x); }

// XLA ErfInv32 (Giles polynomial, w = -log(1-x^2), branch at 5).
__device__ __forceinline__ float erfinv32(float x) {
  float w = -flog(__builtin_fmaf(-x, x, 1.0f));
  float p;
  if (w < 5.0f) {
    w = w - 2.5f;
    p = 2.81022636e-08f;
    p = __builtin_fmaf(p, w, 3.43273939e-07f);
    p = __builtin_fmaf(p, w, -3.5233877e-06f);
    p = __builtin_fmaf(p, w, -4.39150654e-06f);
    p = __builtin_fmaf(p, w, 0.00021858087f);
    p = __builtin_fmaf(p, w, -0.00125372503f);
    p = __builtin_fmaf(p, w, -0.00417768164f);
    p = __builtin_fmaf(p, w, 0.246640727f);
    p = __builtin_fmaf(p, w, 1.50140941f);
  } else {
    w = __fsqrt_rn(w) - 3.0f;
    p = -0.000200214257f;
    p = __builtin_fmaf(p, w, 0.000100950558f);
    p = __builtin_fmaf(p, w, 0.00134934322f);
    p = __builtin_fmaf(p, w, -0.00367342844f);
    p = __builtin_fmaf(p, w, 0.00573950773f);
    p = __builtin_fmaf(p, w, -0.0076224613f);
    p = __builtin_fmaf(p, w, 0.00943887047f);
    p = __builtin_fmaf(p, w, 1.00167406f);
    p = __builtin_fmaf(p, w, 2.83297682f);
  }
  return p * x;
}

// jax.random.normal scalar: u = u01*2 + nextafter(-1,0); sqrt(2)*erfinv(u)
__device__ __forceinline__ float normal_from_bits(uint32_t bits) {
  const float LO = __uint_as_float(0xBF7FFFFFu);   // nextafter(-1,0)
  float u = __builtin_fmaf(bits_to_u01(bits), 2.0f, LO);
  u = fmaxf(LO, u);
  return 1.41421356f * erfinv32(u);
}

// Per-lane persistent work-queue over (sample, gamma-phase) items.
// Bit streams per (element, sample) are IDENTICAL to the lockstep version —
// only wave scheduling changes (a lane advances as soon as ITS draw accepts,
// instead of waiting for all 64 lanes).
__global__ __launch_bounds__(BLOCK) void beta_mc_kernel(
    const float* __restrict__ alpha, const float* __restrict__ beta_,
    const int* __restrict__ cip, const int* __restrict__ valp,
    const int* __restrict__ offp, float* __restrict__ out, int E, int C)
{
  const int e = blockIdx.x;
  const int ci = *cip;
  float thr = (float)(*valp + *offp) / 1000.0f;
  thr = fminf(fmaxf(thr, 0.0f), 1.0f);

  const float av = alpha[e * C + ci];
  const float bv = beta_[e * C + ci];

  // root key data = (0, 42); key_a, key_b = split(root)  [fold-like]
  const K2 root{0u, 42u};
  const K2 ka = tf(root, 0u, 0u);
  const K2 kb = tf(root, 0u, 1u);

  // Marsaglia-Tsang: d = alpha - 1/3, c = (1/3)/sqrt(d); log(d) hoisted.
  const float ONE3 = 0.33333334f;  // f32(1/3)
  const float da = av - ONE3, ca = ONE3 / __fsqrt_rn(da);
  const float db = bv - ONE3, cb = ONE3 / __fsqrt_rn(db);
  const float lda = flog(da), ldb = flog(db);

  // chain init for (phase, sample): key_i = tf(kg,(0,i)); k = split(key_i)[0]
  auto chain0 = [&](int pp, uint32_t ss) -> K2 {
    K2 kg = pp ? kb : ka;
    K2 ki = tf(kg, 0u, ss * (uint32_t)E + (uint32_t)e);
    return tf(ki, 0u, 0u);
  };

  uint32_t s = threadIdx.x;
  int p = 0;                       // 0 = gamma(alpha), 1 = gamma(beta)
  bool alive = (s < NSAMP);
  bool first = true;
  K2 k = chain0(0, s);
  float dcur = da, ccur = ca, ldcur = lda;
  float lga = 0.0f, acc = 0.0f;

  while (__any(alive)) {
    if (alive) {
      if (!first) k = tf(k, 0u, 0u);      // deferred split[0] (only on reject)
      // body: key, x_key, U_key = split(k, 3)
      K2 xk = tf(k, 0u, 1u);
      K2 Uk = tf(k, 0u, 2u);
      float x, v;
      while (true) {
        K2 sk = tf(xk, 0u, 1u);           // x_key, subkey = split(x_key)
        x = normal_from_bits(draw32(sk));
        v = __builtin_fmaf(x, ccur, 1.0f);
        if (v > 0.0f) break;
        xk = tf(xk, 0u, 0u);
      }
      const float X = x * x;
      const float V = v * v * v;
      const float U = bits_to_u01(draw32(Uk));
      first = false;
      // accept test: reject while (U >= 1-0.0331 X^2) && (log U >= X/2 + d(1-V+log V))
      const float logV = flog(V);
      const float sq = 1.0f - 0.0331f * (X * X);
      bool go = (U >= sq) &&
                (flog(U) >= __builtin_fmaf(0.5f, X, dcur * (1.0f - V + logV)));
      if (!go) {
        const float lg = logV + ldcur;    // log-gamma sample
        if (p == 1) {
          // beta combine + sigmoid accumulate
          const float m  = fmaxf(lga, lg);
          const float g1 = fexp(lga - m), g2 = fexp(lg - m);
          const float xb = g1 * frcp(g1 + g2);
          const float z  = (thr - xb) * 100.0f;
          acc += frcp(1.0f + fexp(-z));
          s += BLOCK;
          alive = (s < NSAMP);
        }
        lga = lg;
        p ^= 1;
        if (alive) {
          dcur  = p ? db  : da;
          ccur  = p ? cb  : ca;
          ldcur = p ? ldb : lda;
          k = chain0(p, s);
          first = true;
        }
      }
    }
  }

  // block reduction (wave64 shfl + LDS)
  for (int o = 32; o > 0; o >>= 1) acc += __shfl_down(acc, o, 64);
  __shared__ float ws_[BLOCK / 64];
  const int lane = threadIdx.x & 63, wid = threadIdx.x >> 6;
  if (lane == 0) ws_[wid] = acc;
  __syncthreads();
  if (threadIdx.x == 0) {
    float t = 0.0f;
    #pragma unroll
    for (int w = 0; w < BLOCK / 64; ++w) t += ws_[w];
    float pr = t / 5000.0f;
    out[e] = fminf(fmaxf(pr, 1e-8f), 1.0f - 1e-8f);
  }
}

extern "C" void kernel_launch(void* const* d_in, const int* in_sizes, int n_in,
                              void* d_out, int out_size, void* d_ws, size_t ws_size,
                              hipStream_t stream) {
  const float* alpha = (const float*)d_in[0];
  const float* beta_ = (const float*)d_in[1];
  const int* ci  = (const int*)d_in[2];
  const int* val = (const int*)d_in[3];
  const int* off = (const int*)d_in[4];
  float* out = (float*)d_out;
  const int E = out_size;                 // 64*128 = 8192
  const int C = in_sizes[0] / out_size;   // 4
  beta_mc_kernel<<<dim3(E), dim3(BLOCK), 0, stream>>>(alpha, beta_, ci, val, off, out, E, C);
}

// Round 6
// 1165.138 us; speedup vs baseline: 1.5557x; 1.0296x over previous
//
#include <hip/hip_runtime.h>
#include <stdint.h>

#define NSAMP 5000
#define BLOCK 256

struct K2 { uint32_t a, b; };

// Threefry-2x32, 20 rounds — matches jax/_src/prng.py lowering exactly.
// __builtin_rotateleft32 guarantees v_alignbit_b32 lowering (1 op/rotate).
__device__ __forceinline__ K2 tf(K2 k, uint32_t x0, uint32_t x1) {
  const uint32_t k0 = k.a, k1 = k.b;
  const uint32_t k2 = k0 ^ k1 ^ 0x1BD11BDAu;
  x0 += k0; x1 += k1;
#define R_(r) { x0 += x1; x1 = __builtin_rotateleft32(x1, (r)); x1 ^= x0; }
  R_(13) R_(15) R_(26) R_(6)
  x0 += k1; x1 += k2 + 1u;
  R_(17) R_(29) R_(16) R_(24)
  x0 += k2; x1 += k0 + 2u;
  R_(13) R_(15) R_(26) R_(6)
  x0 += k0; x1 += k1 + 3u;
  R_(17) R_(29) R_(16) R_(24)
  x0 += k1; x1 += k2 + 4u;
  R_(13) R_(15) R_(26) R_(6)
  x0 += k2; x1 += k0 + 5u;
#undef R_
  return K2{x0, x1};
}

// Partitionable-mode scalar random_bits: xor of both threefry output words.
__device__ __forceinline__ uint32_t draw32(K2 key) {
  K2 r = tf(key, 0u, 0u);
  return r.a ^ r.b;
}

// JAX uniform [0,1): bitcast(0x3F800000 | (bits>>9)) - 1
__device__ __forceinline__ float bits_to_u01(uint32_t bits) {
  return __uint_as_float(0x3F800000u | (bits >> 9)) - 1.0f;
}

// Fast transcendentals via gfx950 HW ops (v_log_f32 / v_exp_f32 / v_rcp_f32).
__device__ __forceinline__ float flog(float x) { return __builtin_amdgcn_logf(x) * 0.69314718f; }
__device__ __forceinline__ float fexp(float x) { return __builtin_amdgcn_exp2f(x * 1.44269504f); }
__device__ __forceinline__ float frcp(float x) { return __builtin_amdgcn_rcpf(x); }

// XLA ErfInv32 (Giles polynomial, w = -log(1-x^2), branch at 5).
__device__ __forceinline__ float erfinv32(float x) {
  float w = -flog(__builtin_fmaf(-x, x, 1.0f));
  float p;
  if (w < 5.0f) {
    w = w - 2.5f;
    p = 2.81022636e-08f;
    p = __builtin_fmaf(p, w, 3.43273939e-07f);
    p = __builtin_fmaf(p, w, -3.5233877e-06f);
    p = __builtin_fmaf(p, w, -4.39150654e-06f);
    p = __builtin_fmaf(p, w, 0.00021858087f);
    p = __builtin_fmaf(p, w, -0.00125372503f);
    p = __builtin_fmaf(p, w, -0.00417768164f);
    p = __builtin_fmaf(p, w, 0.246640727f);
    p = __builtin_fmaf(p, w, 1.50140941f);
  } else {
    w = __fsqrt_rn(w) - 3.0f;
    p = -0.000200214257f;
    p = __builtin_fmaf(p, w, 0.000100950558f);
    p = __builtin_fmaf(p, w, 0.00134934322f);
    p = __builtin_fmaf(p, w, -0.00367342844f);
    p = __builtin_fmaf(p, w, 0.00573950773f);
    p = __builtin_fmaf(p, w, -0.0076224613f);
    p = __builtin_fmaf(p, w, 0.00943887047f);
    p = __builtin_fmaf(p, w, 1.00167406f);
    p = __builtin_fmaf(p, w, 2.83297682f);
  }
  return p * x;
}

// jax.random.normal scalar: u = u01*2 + nextafter(-1,0); sqrt(2)*erfinv(u)
__device__ __forceinline__ float normal_from_bits(uint32_t bits) {
  const float LO = __uint_as_float(0xBF7FFFFFu);   // nextafter(-1,0)
  float u = __builtin_fmaf(bits_to_u01(bits), 2.0f, LO);
  u = fmaxf(LO, u);
  return 1.41421356f * erfinv32(u);
}

// Per-lane persistent work-queue with DYNAMIC sample assignment (LDS atomic).
// Bit streams depend only on (element e, sample s) — which lane processes a
// sample is irrelevant, so dynamic stealing preserves bit-exactness while
// removing the 19-vs-20-sample and attempt-count tail imbalance.
__global__ __launch_bounds__(BLOCK) void beta_mc_kernel(
    const float* __restrict__ alpha, const float* __restrict__ beta_,
    const int* __restrict__ cip, const int* __restrict__ valp,
    const int* __restrict__ offp, float* __restrict__ out, int E, int C)
{
  const int e = blockIdx.x;
  const int ci = *cip;
  float thr = (float)(*valp + *offp) / 1000.0f;
  thr = fminf(fmaxf(thr, 0.0f), 1.0f);

  const float av = alpha[e * C + ci];
  const float bv = beta_[e * C + ci];

  // root key data = (0, 42); key_a, key_b = split(root)  [fold-like]
  const K2 root{0u, 42u};
  const K2 ka = tf(root, 0u, 0u);
  const K2 kb = tf(root, 0u, 1u);

  // Marsaglia-Tsang: d = alpha - 1/3, c = (1/3)/sqrt(d); log(d) hoisted.
  const float ONE3 = 0.33333334f;  // f32(1/3)
  const float da = av - ONE3, ca = ONE3 / __fsqrt_rn(da);
  const float db = bv - ONE3, cb = ONE3 / __fsqrt_rn(db);
  const float lda = flog(da), ldb = flog(db);

  // chain init for (phase, sample): key_i = tf(kg,(0,i)); k = split(key_i)[0]
  auto chain0 = [&](int pp, uint32_t ss) -> K2 {
    K2 kg = pp ? kb : ka;
    K2 ki = tf(kg, 0u, ss * (uint32_t)E + (uint32_t)e);
    return tf(ki, 0u, 0u);
  };

  __shared__ uint32_t next_s;
  if (threadIdx.x == 0) next_s = BLOCK;   // samples 0..BLOCK-1 pre-assigned
  __syncthreads();

  uint32_t s = threadIdx.x;
  int p = 0;                       // 0 = gamma(alpha), 1 = gamma(beta)
  bool alive = true;               // NSAMP > BLOCK
  bool first = true;
  K2 k = chain0(0, s);
  float dcur = da, ccur = ca, ldcur = lda;
  float lga = 0.0f, acc = 0.0f;

  while (__any(alive)) {
    if (alive) {
      if (!first) k = tf(k, 0u, 0u);      // deferred split[0] (only on reject)
      // body: key, x_key, U_key = split(k, 3)
      K2 xk = tf(k, 0u, 1u);
      K2 Uk = tf(k, 0u, 2u);
      float x, v;
      while (true) {
        K2 sk = tf(xk, 0u, 1u);           // x_key, subkey = split(x_key)
        x = normal_from_bits(draw32(sk));
        v = __builtin_fmaf(x, ccur, 1.0f);
        if (v > 0.0f) break;
        xk = tf(xk, 0u, 0u);
      }
      const float X = x * x;
      const float V = v * v * v;
      const float U = bits_to_u01(draw32(Uk));
      first = false;
      // accept test: reject while (U >= 1-0.0331 X^2) && (log U >= X/2 + d(1-V+log V))
      const float logV = flog(V);
      const float sq = 1.0f - 0.0331f * (X * X);
      bool go = (U >= sq) &&
                (flog(U) >= __builtin_fmaf(0.5f, X, dcur * (1.0f - V + logV)));
      if (!go) {
        const float lg = logV + ldcur;    // log-gamma sample
        if (p == 1) {
          // beta combine: x = ga/(ga+gb) == sigmoid(lga - lgb); then sigmoid accumulate
          const float xb = frcp(1.0f + fexp(lg - lga));
          const float z  = (thr - xb) * 100.0f;
          acc += frcp(1.0f + fexp(-z));
          s = atomicAdd(&next_s, 1u);     // grab next sample (LDS)
          alive = (s < NSAMP);
          p = 0;
        } else {
          p = 1;
        }
        lga = lg;
        if (alive) {
          dcur  = p ? db  : da;
          ccur  = p ? cb  : ca;
          ldcur = p ? ldb : lda;
          k = chain0(p, s);
          first = true;
        }
      }
    }
  }

  // block reduction (wave64 shfl + LDS)
  for (int o = 32; o > 0; o >>= 1) acc += __shfl_down(acc, o, 64);
  __shared__ float ws_[BLOCK / 64];
  const int lane = threadIdx.x & 63, wid = threadIdx.x >> 6;
  if (lane == 0) ws_[wid] = acc;
  __syncthreads();
  if (threadIdx.x == 0) {
    float t = 0.0f;
    #pragma unroll
    for (int w = 0; w < BLOCK / 64; ++w) t += ws_[w];
    float pr = t / 5000.0f;
    out[e] = fminf(fmaxf(pr, 1e-8f), 1.0f - 1e-8f);
  }
}

extern "C" void kernel_launch(void* const* d_in, const int* in_sizes, int n_in,
                              void* d_out, int out_size, void* d_ws, size_t ws_size,
                              hipStream_t stream) {
  const float* alpha = (const float*)d_in[0];
  const float* beta_ = (const float*)d_in[1];
  const int* ci  = (const int*)d_in[2];
  const int* val = (const int*)d_in[3];
  const int* off = (const int*)d_in[4];
  float* out = (float*)d_out;
  const int E = out_size;                 // 64*128 = 8192
  const int C = in_sizes[0] / out_size;   // 4
  beta_mc_kernel<<<dim3(E), dim3(BLOCK), 0, stream>>>(alpha, beta_, ci, val, off, out, E, C);
}

// Round 7
// 1160.440 us; speedup vs baseline: 1.5620x; 1.0040x over previous
//
#include <hip/hip_runtime.h>
#include <stdint.h>

#define NSAMP 5000
#define BLOCK 256

struct K2 { uint32_t a, b; };

// Threefry-2x32, 20 rounds — matches jax/_src/prng.py lowering exactly.
__device__ __forceinline__ K2 tf(K2 k, uint32_t x0, uint32_t x1) {
  const uint32_t k0 = k.a, k1 = k.b;
  const uint32_t k2 = k0 ^ k1 ^ 0x1BD11BDAu;
  x0 += k0; x1 += k1;
#define R_(r) { x0 += x1; x1 = __builtin_rotateleft32(x1, (r)); x1 ^= x0; }
  R_(13) R_(15) R_(26) R_(6)
  x0 += k1; x1 += k2 + 1u;
  R_(17) R_(29) R_(16) R_(24)
  x0 += k2; x1 += k0 + 2u;
  R_(13) R_(15) R_(26) R_(6)
  x0 += k0; x1 += k1 + 3u;
  R_(17) R_(29) R_(16) R_(24)
  x0 += k1; x1 += k2 + 4u;
  R_(13) R_(15) R_(26) R_(6)
  x0 += k2; x1 += k0 + 5u;
#undef R_
  return K2{x0, x1};
}

// Partitionable-mode scalar random_bits: xor of both threefry output words.
__device__ __forceinline__ uint32_t draw32(K2 key) {
  K2 r = tf(key, 0u, 0u);
  return r.a ^ r.b;
}

// JAX uniform [0,1): bitcast(0x3F800000 | (bits>>9)) - 1
__device__ __forceinline__ float bits_to_u01(uint32_t bits) {
  return __uint_as_float(0x3F800000u | (bits >> 9)) - 1.0f;
}

// Fast transcendentals via gfx950 HW ops (v_log_f32 / v_exp_f32 / v_rcp_f32).
__device__ __forceinline__ float flog(float x) { return __builtin_amdgcn_logf(x) * 0.69314718f; }
__device__ __forceinline__ float fexp(float x) { return __builtin_amdgcn_exp2f(x * 1.44269504f); }
__device__ __forceinline__ float frcp(float x) { return __builtin_amdgcn_rcpf(x); }

// XLA ErfInv32 (Giles polynomial, w = -log(1-x^2), branch at 5).
__device__ __forceinline__ float erfinv32(float x) {
  float w = -flog(__builtin_fmaf(-x, x, 1.0f));
  float p;
  if (w < 5.0f) {
    w = w - 2.5f;
    p = 2.81022636e-08f;
    p = __builtin_fmaf(p, w, 3.43273939e-07f);
    p = __builtin_fmaf(p, w, -3.5233877e-06f);
    p = __builtin_fmaf(p, w, -4.39150654e-06f);
    p = __builtin_fmaf(p, w, 0.00021858087f);
    p = __builtin_fmaf(p, w, -0.00125372503f);
    p = __builtin_fmaf(p, w, -0.00417768164f);
    p = __builtin_fmaf(p, w, 0.246640727f);
    p = __builtin_fmaf(p, w, 1.50140941f);
  } else {
    w = __fsqrt_rn(w) - 3.0f;
    p = -0.000200214257f;
    p = __builtin_fmaf(p, w, 0.000100950558f);
    p = __builtin_fmaf(p, w, 0.00134934322f);
    p = __builtin_fmaf(p, w, -0.00367342844f);
    p = __builtin_fmaf(p, w, 0.00573950773f);
    p = __builtin_fmaf(p, w, -0.0076224613f);
    p = __builtin_fmaf(p, w, 0.00943887047f);
    p = __builtin_fmaf(p, w, 1.00167406f);
    p = __builtin_fmaf(p, w, 2.83297682f);
  }
  return p * x;
}

// jax.random.normal scalar: u = fma(u01, 2, LO); sqrt(2)*erfinv(u).
// max(LO,u) is provably redundant: u01 >= 0 and round-to-nearest of a sum
// >= LO cannot land below LO — bit-identical without it.
__device__ __forceinline__ float normal_from_bits(uint32_t bits) {
  const float LO = __uint_as_float(0xBF7FFFFFu);   // nextafter(-1,0)
  float u = __builtin_fmaf(bits_to_u01(bits), 2.0f, LO);
  return 1.41421356f * erfinv32(u);
}

// Per-lane persistent work-queue with dynamic sample assignment (LDS atomic).
// Bit streams depend only on (element e, sample s); scheduling is free.
__global__ __launch_bounds__(BLOCK) void beta_mc_kernel(
    const float* __restrict__ alpha, const float* __restrict__ beta_,
    const int* __restrict__ cip, const int* __restrict__ valp,
    const int* __restrict__ offp, float* __restrict__ out, int E, int C)
{
  const int e = blockIdx.x;
  const int ci = *cip;
  float thr = (float)(*valp + *offp) / 1000.0f;
  thr = fminf(fmaxf(thr, 0.0f), 1.0f);

  const float av = alpha[e * C + ci];
  const float bv = beta_[e * C + ci];

  // root key data = (0, 42); key_a, key_b = split(root)  [fold-like]
  const K2 root{0u, 42u};
  const K2 ka = tf(root, 0u, 0u);
  const K2 kb = tf(root, 0u, 1u);

  // Marsaglia-Tsang: d = alpha - 1/3, c = (1/3)/sqrt(d); log(d) hoisted.
  const float ONE3 = 0.33333334f;  // f32(1/3)
  const float da = av - ONE3, ca = ONE3 / __fsqrt_rn(da);
  const float db = bv - ONE3, cb = ONE3 / __fsqrt_rn(db);
  const float lda = flog(da), ldb = flog(db);

  // chain init for (phase, sample): key_i = tf(kg,(0,i)); k = split(key_i)[0]
  auto chain0 = [&](int pp, uint32_t ss) -> K2 {
    K2 kg = pp ? kb : ka;
    K2 ki = tf(kg, 0u, ss * (uint32_t)E + (uint32_t)e);
    return tf(ki, 0u, 0u);
  };

  __shared__ uint32_t next_s;
  if (threadIdx.x == 0) next_s = BLOCK;   // samples 0..BLOCK-1 pre-assigned
  __syncthreads();

  uint32_t s = threadIdx.x;
  int p = 0;                       // 0 = gamma(alpha), 1 = gamma(beta)
  bool alive = true;               // NSAMP > BLOCK
  K2 k = chain0(0, s);
  float dcur = da, ccur = ca, ldcur = lda;
  float lga = 0.0f, acc = 0.0f;

  while (__any(alive)) {
    if (alive) {
      // body: key, x_key, U_key = split(k, 3)  (split[0] applied on reject below)
      K2 xk = tf(k, 0u, 1u);
      K2 Uk = tf(k, 0u, 2u);
      float x, v;
      while (true) {
        K2 sk = tf(xk, 0u, 1u);           // x_key, subkey = split(x_key)
        x = normal_from_bits(draw32(sk));
        v = __builtin_fmaf(x, ccur, 1.0f);
        if (v > 0.0f) break;
        xk = tf(xk, 0u, 0u);
      }
      const float X = x * x;
      const float V = v * v * v;
      const float U = bits_to_u01(draw32(Uk));
      // branchless accept test (flog(U) unconditional — no nested exec region):
      // reject while (U >= 1-0.0331 X^2) && (log U >= X/2 + d(1-V+log V))
      const float logV = flog(V);
      const float logU = flog(U);
      const float sq  = __builtin_fmaf(-0.0331f, X * X, 1.0f);
      const float rhs = __builtin_fmaf(0.5f, X, dcur * (1.0f - V + logV));
      const bool rej = (U >= sq) & (logU >= rhs);
      if (rej) {
        k = tf(k, 0u, 0u);                // carried split[0] (reject only)
      } else {
        const float lg = logV + ldcur;    // log-gamma sample
        if (p == 1) {
          // beta combine: x = ga/(ga+gb) == sigmoid(lga - lgb); sigmoid accumulate
          const float xb = frcp(1.0f + fexp(lg - lga));
          const float z  = (thr - xb) * 100.0f;
          acc += frcp(1.0f + fexp(-z));
          s = atomicAdd(&next_s, 1u);     // grab next sample (LDS)
          alive = (s < NSAMP);
          p = 0;
        } else {
          p = 1;
        }
        lga = lg;
        if (alive) {
          dcur  = p ? db  : da;
          ccur  = p ? cb  : ca;
          ldcur = p ? ldb : lda;
          k = chain0(p, s);
        }
      }
    }
  }

  // block reduction (wave64 shfl + LDS)
  for (int o = 32; o > 0; o >>= 1) acc += __shfl_down(acc, o, 64);
  __shared__ float ws_[BLOCK / 64];
  const int lane = threadIdx.x & 63, wid = threadIdx.x >> 6;
  if (lane == 0) ws_[wid] = acc;
  __syncthreads();
  if (threadIdx.x == 0) {
    float t = 0.0f;
    #pragma unroll
    for (int w = 0; w < BLOCK / 64; ++w) t += ws_[w];
    float pr = t / 5000.0f;
    out[e] = fminf(fmaxf(pr, 1e-8f), 1.0f - 1e-8f);
  }
}

extern "C" void kernel_launch(void* const* d_in, const int* in_sizes, int n_in,
                              void* d_out, int out_size, void* d_ws, size_t ws_size,
                              hipStream_t stream) {
  const float* alpha = (const float*)d_in[0];
  const float* beta_ = (const float*)d_in[1];
  const int* ci  = (const int*)d_in[2];
  const int* val = (const int*)d_in[3];
  const int* off = (const int*)d_in[4];
  float* out = (float*)d_out;
  const int E = out_size;                 // 64*128 = 8192
  const int C = in_sizes[0] / out_size;   // 4
  beta_mc_kernel<<<dim3(E), dim3(BLOCK), 0, stream>>>(alpha, beta_, ci, val, off, out, E, C);
}